// Round 8
// baseline (1074.965 us; speedup 1.0000x reference)
//
#include <hip/hip_runtime.h>
#include <math.h>

#define BB 1024
#define TT 512
#define FF 32
#define HH 64
#define GG 256   // 4H
#define TC 64
#define NCHUNK (TT/TC)   // 8
#define MB 16            // batch rows per block
#define NBLK (BB/MB)     // 64
#define HPAD 68          // h_lds row stride
#define ZSTRIDE 20       // zx row stride (pad: 2-way max bank aliasing, 16B aligned)
#define EPSBN 1e-3f

typedef __attribute__((ext_vector_type(8))) short bf16x8;
typedef __attribute__((ext_vector_type(4))) float f32x4;
typedef __attribute__((ext_vector_type(4))) int   i32x4;

// ---------------- fold1: per-layer BN vectors + attention vector ----------------
__global__ void fold1_kernel(const float* __restrict__ gamma, const float* __restrict__ beta,
                             const float* __restrict__ mean, const float* __restrict__ var,
                             const float* __restrict__ attw, const float* __restrict__ attv,
                             float* __restrict__ s_out, float* __restrict__ ab_out,
                             float* __restrict__ wv_out) {
    int d = threadIdx.x; // 64 threads
    float s = gamma[d] * rsqrtf(var[d] + EPSBN);
    float ab = beta[d] - mean[d] * s;
    float wvr = 0.f;
    for (int e = 0; e < HH; ++e) wvr += attw[d * HH + e] * attv[e];
    s_out[d] = s;
    ab_out[d] = ab;
    wv_out[d] = s * wvr;
}

// ---------------- fold2: fold previous layer's BN into next W, b ----------------
__global__ void fold2_kernel(const float* __restrict__ W, const float* __restrict__ b,
                             const float* __restrict__ s_prev, const float* __restrict__ ab_prev,
                             float* __restrict__ Wp, float* __restrict__ bp) {
    int g = threadIdx.x; // 256 threads
    float bacc = b[g];
    for (int d = 0; d < HH; ++d) {
        float w = W[d * GG + g];
        bacc += ab_prev[d] * w;
        Wp[d * GG + g] = s_prev[d] * w;
    }
    bp[g] = bacc;
}

// ---------------- init per-call state ----------------
__global__ void init_kernel(float* st_h, float* st_c, float* st_acc, float* st_m, float* st_d) {
    int i = blockIdx.x * blockDim.x + threadIdx.x;
    int n = 3 * BB * HH;
    if (i < n) { st_h[i] = 0.f; st_c[i] = 0.f; st_acc[i] = 0.f; }
    if (i < 3 * BB) { st_m[i] = -3.0e38f; st_d[i] = 0.f; }
}

// ---------------- helpers ----------------
__device__ __forceinline__ f32x4 ld4(const float* p) { return *reinterpret_cast<const f32x4*>(p); }
__device__ __forceinline__ void st4(float* p, f32x4 v) { *reinterpret_cast<f32x4*>(p) = v; }
__device__ __forceinline__ int cvtpk(float a, float b) {
    int r; asm("v_cvt_pk_bf16_f32 %0, %1, %2" : "=v"(r) : "v"(a), "v"(b)); return r;
}
// split 8 fp32 (k-order) into hi/lo bf16x8 fragments (hi RNE; lo = residual)
__device__ __forceinline__ void mkfrag(f32x4 A, f32x4 B, bf16x8& hi, bf16x8& lo) {
    i32x4 H, L;
    H[0] = cvtpk(A[0], A[1]); H[1] = cvtpk(A[2], A[3]);
    H[2] = cvtpk(B[0], B[1]); H[3] = cvtpk(B[2], B[3]);
    L[0] = cvtpk(A[0] - __int_as_float(H[0] << 16), A[1] - __int_as_float(H[0] & 0xffff0000));
    L[1] = cvtpk(A[2] - __int_as_float(H[1] << 16), A[3] - __int_as_float(H[1] & 0xffff0000));
    L[2] = cvtpk(B[0] - __int_as_float(H[2] << 16), B[1] - __int_as_float(H[2] & 0xffff0000));
    L[3] = cvtpk(B[2] - __int_as_float(H[3] << 16), B[3] - __int_as_float(H[3] & 0xffff0000));
    hi = __builtin_bit_cast(bf16x8, H); lo = __builtin_bit_cast(bf16x8, L);
}
__device__ __forceinline__ float sigm(float x) { return __fdividef(1.f, 1.f + __expf(-x)); }
#define MFMA(a, b, c) c = __builtin_amdgcn_mfma_f32_16x16x32_bf16(a, b, c, 0, 0, 0)

// ---------------- producer/consumer MFMA recurrent kernel ----------------
// Block = 16 batch rows, 8 waves (2/SIMD). Waves 0-3 (R): recurrence — U-MFMAs onto
// z_x seeds read from LDS ring, activation, c/h update, h publish. Waves 4-7 (P):
// produce z_x = bias + W.x one step ahead into the 2-slot ring (no recurrence dep),
// plus online-softmax attention and Hout staging. One barrier per timestep.
// Slot discipline: R reads zx[t&1]; P writes zx[(t&1)^1] — disjoint, 1-barrier vis.
struct RecFArgs {
    const float* xin[3]; long sB[3]; long sT[3]; int K[3];
    const float* W[3]; const float* U[3]; const float* bias[3];
    float* Hout[3];              // nullptr -> skip
    float* st_h[3]; float* st_c[3]; float* st_acc[3];
    float* st_m[3]; float* st_d[3];
    const float* wv[3]; const float* abv[3]; const float* sbn[3];
    float* a_out[3];
    int last[3]; int first[3];
};

template<int KT>   // x K-tiles: 1 (K=32, layer1) or 2 (K=64)
__device__ __forceinline__ void rec_body(const RecFArgs& A, const int seg, const int b0,
                                         float* zx, float (*hl)[MB][HPAD]) {
    const int tid = threadIdx.x;
    const int wall = tid >> 6;        // 0..7
    const int w = wall & 3;
    const bool isP = wall >= 4;
    const int l = tid & 63;
    const int r = l & 15;
    const int q = l >> 4;
    const int cw = w << 4;
    const int grow = b0 + r;

    auto zxo = [&](int slot, int g) {
        return (((slot * 4 + w) * 4 + g) * 16 + r) * ZSTRIDE + 4 * q;
    };

    if (!isP) {
        // ================= R-waves: recurrence =================
        bf16x8 UHf[4][2], ULf[4][2];
        const float* Up = A.U[seg];
#pragma unroll
        for (int g = 0; g < 4; ++g)
#pragma unroll
            for (int kk = 0; kk < 2; ++kk) {
                const float* p = Up + (size_t)(32 * kk + 8 * q) * GG + 64 * g + cw + r;
                f32x4 a, b;
                a[0] = p[0];      a[1] = p[GG];     a[2] = p[2 * GG]; a[3] = p[3 * GG];
                b[0] = p[4 * GG]; b[1] = p[5 * GG]; b[2] = p[6 * GG]; b[3] = p[7 * GG];
                mkfrag(a, b, UHf[g][kk], ULf[g][kk]);
            }
        f32x4 c4 = ld4(A.st_c[seg] + (size_t)grow * HH + cw + 4 * q);
        f32x4 h4 = ld4(A.st_h[seg] + (size_t)grow * HH + cw + 4 * q);
        st4(&hl[0][r][cw + 4 * q], h4);
        __syncthreads();

#pragma unroll 1
        for (int t = 0; t < TC; ++t) {
            const int pr = t & 1;
            f32x4 C[4];
#pragma unroll
            for (int g = 0; g < 4; ++g) C[g] = ld4(zx + zxo(pr, g));
            f32x4 f0 = ld4(&hl[pr][r][8 * q]);
            f32x4 f1 = ld4(&hl[pr][r][8 * q + 4]);
            f32x4 f2 = ld4(&hl[pr][r][32 + 8 * q]);
            f32x4 f3 = ld4(&hl[pr][r][32 + 8 * q + 4]);
            bf16x8 bh0, bl0, bh1, bl1;
            mkfrag(f0, f1, bh0, bl0);
            mkfrag(f2, f3, bh1, bl1);
#pragma unroll
            for (int g = 0; g < 4; ++g) {
                MFMA(UHf[g][0], bh0, C[g]);
                MFMA(UHf[g][0], bl0, C[g]);
                MFMA(ULf[g][0], bh0, C[g]);
                MFMA(UHf[g][1], bh1, C[g]);
                MFMA(UHf[g][1], bl1, C[g]);
                MFMA(ULf[g][1], bh1, C[g]);
            }
#pragma unroll
            for (int i = 0; i < 4; ++i) {
                float zi = sigm(C[0][i]);
                float zf = sigm(C[1][i]);
                float zg = fmaxf(C[2][i], 0.f);
                float zo = sigm(C[3][i]);
                c4[i] = fmaf(zf, c4[i], zi * zg);
                h4[i] = zo * fmaxf(c4[i], 0.f);
            }
            st4(&hl[pr ^ 1][r][cw + 4 * q], h4);
            __syncthreads();
        }
        st4(A.st_c[seg] + (size_t)grow * HH + cw + 4 * q, c4);
        st4(A.st_h[seg] + (size_t)grow * HH + cw + 4 * q, h4);
    } else {
        // ================= P-waves: z_x producer + attention + Hout =================
        bf16x8 WHf[4][KT], WLf[4][KT];
        const float* Wp = A.W[seg];
#pragma unroll
        for (int g = 0; g < 4; ++g)
#pragma unroll
            for (int kk = 0; kk < KT; ++kk) {
                const float* p = Wp + (size_t)(32 * kk + 8 * q) * GG + 64 * g + cw + r;
                f32x4 a, b;
                a[0] = p[0];      a[1] = p[GG];     a[2] = p[2 * GG]; a[3] = p[3 * GG];
                b[0] = p[4 * GG]; b[1] = p[5 * GG]; b[2] = p[6 * GG]; b[3] = p[7 * GG];
                mkfrag(a, b, WHf[g][kk], WLf[g][kk]);
            }
        f32x4 bias4[4];
#pragma unroll
        for (int g = 0; g < 4; ++g) bias4[g] = ld4(A.bias[seg] + 64 * g + cw + 4 * q);
        f32x4 wva = ld4(A.wv[seg] + 8 * q);
        f32x4 wvb = ld4(A.wv[seg] + 8 * q + 4);
        f32x4 wvc = ld4(A.wv[seg] + 32 + 8 * q);
        f32x4 wvd = ld4(A.wv[seg] + 32 + 8 * q + 4);
        f32x4 acc4 = ld4(A.st_acc[seg] + (size_t)grow * HH + cw + 4 * q);
        float m_b = A.st_m[seg][grow];
        float d_b = A.st_d[seg][grow];

        const float* xbase = A.xin[seg] + (size_t)grow * A.sB[seg];
        const long sT = A.sT[seg];
        auto xload = [&](f32x4 (&X)[2 * KT], int t) {
            const float* xp = xbase + (size_t)t * sT + 8 * q;
            X[0] = ld4(xp); X[1] = ld4(xp + 4);
            if constexpr (KT == 2) { X[2] = ld4(xp + 32); X[3] = ld4(xp + 32 + 4); }
        };
        auto produce = [&](int slot, f32x4 (&X)[2 * KT]) {
            bf16x8 xh0, xl0, xh1, xl1;
            mkfrag(X[0], X[1], xh0, xl0);
            if constexpr (KT == 2) mkfrag(X[2], X[3], xh1, xl1);
#pragma unroll
            for (int g = 0; g < 4; ++g) {
                f32x4 Cx = bias4[g];
                MFMA(WHf[g][0], xh0, Cx);
                MFMA(WHf[g][0], xl0, Cx);
                MFMA(WLf[g][0], xh0, Cx);
                if constexpr (KT == 2) {
                    MFMA(WHf[g][1], xh1, Cx);
                    MFMA(WHf[g][1], xl1, Cx);
                    MFMA(WLf[g][1], xh1, Cx);
                }
                st4(zx + zxo(slot, g), Cx);
            }
        };
        auto attup = [&](int pr) {   // online softmax on h in hl[pr]
            f32x4 f0 = ld4(&hl[pr][r][8 * q]);
            f32x4 f1 = ld4(&hl[pr][r][8 * q + 4]);
            f32x4 f2 = ld4(&hl[pr][r][32 + 8 * q]);
            f32x4 f3 = ld4(&hl[pr][r][32 + 8 * q + 4]);
            float sc = 0.f;
#pragma unroll
            for (int i = 0; i < 4; ++i) {
                sc = fmaf(f0[i], wva[i], sc);
                sc = fmaf(f1[i], wvb[i], sc);
                sc = fmaf(f2[i], wvc[i], sc);
                sc = fmaf(f3[i], wvd[i], sc);
            }
            sc += __shfl_xor(sc, 16);
            sc += __shfl_xor(sc, 32);
            f32x4 hp4 = ld4(&hl[pr][r][cw + 4 * q]);
            float mn = fmaxf(m_b, sc);
            float corr = __expf(m_b - mn);
            float p = __expf(sc - mn);
            d_b = d_b * corr + p;
            acc4 = acc4 * corr + p * hp4;
            m_b = mn;
        };
        float* Hob = A.Hout[seg];
        auto stage = [&](int pr, int tt) {   // all 4 P-waves: 4 rows each
            const int sr = (w << 2) + q;
            f32x4 v = ld4(&hl[pr][sr][4 * r]);
            st4(Hob + (size_t)(b0 + sr) * (TC * HH) + (size_t)tt * HH + 4 * r, v);
        };

        // prologue: seed zx[0] (t=0); prefetch x1 -> XA, x2 -> XB
        f32x4 X0[2 * KT], XA[2 * KT], XB[2 * KT];
        xload(X0, 0);
        produce(0, X0);
        xload(XA, 1);
        xload(XB, 2 < TC ? 2 : TC - 1);
        __syncthreads();

        const bool first = A.first[seg] != 0;
#pragma unroll 1
        for (int t = 0; t < TC; ++t) {
            const int pr = t & 1;
            if (t + 1 < TC) {
                if (pr == 0) produce(1, XA); else produce(0, XB);
            }
            {   // refill used buffer with x_{t+3} (2-step latency budget)
                int tn = t + 3 < TC ? t + 3 : TC - 1;
                if (pr == 0) xload(XA, tn); else xload(XB, tn);
            }
            if (!(first && t == 0)) attup(pr);
            if (Hob && t > 0) stage(pr, t - 1);
            __syncthreads();
        }
        // epilogue (TC even -> h_{TC-1} sits in hl[0])
        if (Hob) stage(0, TC - 1);
        if (A.last[seg]) attup(0);
        st4(A.st_acc[seg] + (size_t)grow * HH + cw + 4 * q, acc4);
        if (w == 0 && q == 0) { A.st_m[seg][grow] = m_b; A.st_d[seg][grow] = d_b; }
        if (A.last[seg]) {
            f32x4 sb = ld4(A.sbn[seg] + cw + 4 * q);
            f32x4 ab = ld4(A.abv[seg] + cw + 4 * q);
            f32x4 res;
#pragma unroll
            for (int i = 0; i < 4; ++i)
                res[i] = sb[i] * __fdividef(acc4[i], d_b) + ab[i];
            st4(A.a_out[seg] + (size_t)grow * HH + cw + 4 * q, res);
        }
    }
}

__global__ __launch_bounds__(512, 2) void rec_pc(RecFArgs A) {
    __shared__ float zx[2 * 4 * 4 * 16 * ZSTRIDE];   // 40 KB: 2-slot z_x ring
    __shared__ float hl[2][MB][HPAD];                // 8.7 KB
    const int seg = blockIdx.x >> 6;                 // NBLK = 64
    const int b0 = (blockIdx.x & (NBLK - 1)) << 4;
    if (A.K[seg] == 32) rec_body<1>(A, seg, b0, zx, hl);
    else                rec_body<2>(A, seg, b0, zx, hl);
}

// ---------------- final: out[b] = db + sum_{l,j} a[l][b][j]*dw[l*64+j] ----------------
__global__ void final_kernel(const float* __restrict__ a, const float* __restrict__ dw,
                             const float* __restrict__ db, float* __restrict__ out) {
    int b = blockIdx.x * blockDim.x + threadIdx.x;
    if (b >= BB) return;
    float acc = db[0];
    for (int l = 0; l < 3; ++l)
        for (int j = 0; j < HH; ++j)
            acc += a[(l * BB + b) * HH + j] * dw[l * HH + j];
    out[b] = acc;
}

extern "C" void kernel_launch(void* const* d_in, const int* in_sizes, int n_in,
                              void* d_out, int out_size, void* d_ws, size_t ws_size,
                              hipStream_t stream) {
    (void)in_sizes; (void)n_in; (void)out_size; (void)ws_size;
    const float* x = (const float*)d_in[0];
    const float* w[3]    = {(const float*)d_in[1],  (const float*)d_in[10], (const float*)d_in[19]};
    const float* uu[3]   = {(const float*)d_in[2],  (const float*)d_in[11], (const float*)d_in[20]};
    const float* bi[3]   = {(const float*)d_in[3],  (const float*)d_in[12], (const float*)d_in[21]};
    const float* gam[3]  = {(const float*)d_in[4],  (const float*)d_in[13], (const float*)d_in[22]};
    const float* bet[3]  = {(const float*)d_in[5],  (const float*)d_in[14], (const float*)d_in[23]};
    const float* mea[3]  = {(const float*)d_in[6],  (const float*)d_in[15], (const float*)d_in[24]};
    const float* var[3]  = {(const float*)d_in[7],  (const float*)d_in[16], (const float*)d_in[25]};
    const float* atw[3]  = {(const float*)d_in[8],  (const float*)d_in[17], (const float*)d_in[26]};
    const float* atv[3]  = {(const float*)d_in[9],  (const float*)d_in[18], (const float*)d_in[27]};
    const float* dw = (const float*)d_in[28];
    const float* db = (const float*)d_in[29];

    float* ws = (float*)d_ws;
    size_t off = 0;
    float* Hb[2][2];
    for (int l = 0; l < 2; ++l)
        for (int p = 0; p < 2; ++p) { Hb[l][p] = ws + off; off += (size_t)BB * TC * HH; }
    float* st_h  = ws + off; off += 3 * BB * HH;
    float* st_c  = ws + off; off += 3 * BB * HH;
    float* st_ac = ws + off; off += 3 * BB * HH;
    float* st_m  = ws + off; off += 3 * BB;
    float* st_d  = ws + off; off += 3 * BB;
    float* s_ws  = ws + off; off += 3 * HH;
    float* ab_ws = ws + off; off += 3 * HH;
    float* wv_ws = ws + off; off += 3 * HH;
    float* W2p   = ws + off; off += HH * GG;
    float* W3p   = ws + off; off += HH * GG;
    float* b2p   = ws + off; off += GG;
    float* b3p   = ws + off; off += GG;
    float* a_ws  = ws + off; off += 3 * BB * HH;

    for (int l = 0; l < 3; ++l)
        fold1_kernel<<<1, 64, 0, stream>>>(gam[l], bet[l], mea[l], var[l], atw[l], atv[l],
                                           s_ws + l * HH, ab_ws + l * HH, wv_ws + l * HH);
    fold2_kernel<<<1, 256, 0, stream>>>(w[1], bi[1], s_ws + 0 * HH, ab_ws + 0 * HH, W2p, b2p);
    fold2_kernel<<<1, 256, 0, stream>>>(w[2], bi[2], s_ws + 1 * HH, ab_ws + 1 * HH, W3p, b3p);
    init_kernel<<<(3 * BB * HH + 255) / 256, 256, 0, stream>>>(st_h, st_c, st_ac, st_m, st_d);

    const float* Wl[3] = {w[0], W2p, W3p};
    const float* bl[3] = {bi[0], b2p, b3p};

    // software pipeline: at step s, layer l processes chunk s-l
    for (int s = 0; s <= NCHUNK - 1 + 2; ++s) {
        RecFArgs ra;
        int nseg = 0;
        for (int l = 0; l < 3; ++l) {
            int cpos = s - l;
            if (cpos < 0 || cpos >= NCHUNK) continue;
            if (l == 0) {
                ra.xin[nseg] = x + (size_t)cpos * TC * FF;
                ra.sB[nseg] = (long)TT * FF;
                ra.sT[nseg] = FF;
                ra.K[nseg] = 32;
            } else {
                ra.xin[nseg] = Hb[l - 1][(s & 1) ^ 1];   // written by layer l-1 at step s-1
                ra.sB[nseg] = (long)TC * HH;
                ra.sT[nseg] = HH;
                ra.K[nseg] = 64;
            }
            ra.W[nseg] = Wl[l]; ra.U[nseg] = uu[l]; ra.bias[nseg] = bl[l];
            ra.Hout[nseg] = (l < 2) ? Hb[l][s & 1] : (float*)0;
            ra.st_h[nseg] = st_h + l * BB * HH;
            ra.st_c[nseg] = st_c + l * BB * HH;
            ra.st_acc[nseg] = st_ac + l * BB * HH;
            ra.st_m[nseg] = st_m + l * BB;
            ra.st_d[nseg] = st_d + l * BB;
            ra.wv[nseg]  = wv_ws + l * HH;
            ra.abv[nseg] = ab_ws + l * HH;
            ra.sbn[nseg] = s_ws + l * HH;
            ra.a_out[nseg] = a_ws + l * BB * HH;
            ra.last[nseg]  = (cpos == NCHUNK - 1) ? 1 : 0;
            ra.first[nseg] = (cpos == 0) ? 1 : 0;
            ++nseg;
        }
        if (!nseg) continue;
        rec_pc<<<nseg * NBLK, 512, 0, stream>>>(ra);
    }
    final_kernel<<<(BB + 255) / 256, 256, 0, stream>>>(a_ws, dw, db, (float*)d_out);
}

// Round 9
// 800.182 us; speedup vs baseline: 1.3434x; 1.3434x over previous
//
#include <hip/hip_runtime.h>
#include <math.h>

#define BB 1024
#define TT 512
#define FF 32
#define HH 64
#define GG 256   // 4H
#define TC 64
#define NCHUNK (TT/TC)   // 8
#define MB 16            // batch rows per block
#define NBLK (BB/MB)     // 64
#define HPAD 68          // h_lds row stride
#define EPSBN 1e-3f

typedef __attribute__((ext_vector_type(8))) short bf16x8;
typedef __attribute__((ext_vector_type(4))) float f32x4;
typedef __attribute__((ext_vector_type(4))) int   i32x4;
typedef unsigned short ushort_t;

// ---------------- fold1: per-layer BN vectors + attention vector ----------------
__global__ void fold1_kernel(const float* __restrict__ gamma, const float* __restrict__ beta,
                             const float* __restrict__ mean, const float* __restrict__ var,
                             const float* __restrict__ attw, const float* __restrict__ attv,
                             float* __restrict__ s_out, float* __restrict__ ab_out,
                             float* __restrict__ wv_out) {
    int d = threadIdx.x; // 64 threads
    float s = gamma[d] * rsqrtf(var[d] + EPSBN);
    float ab = beta[d] - mean[d] * s;
    float wvr = 0.f;
    for (int e = 0; e < HH; ++e) wvr += attw[d * HH + e] * attv[e];
    s_out[d] = s;
    ab_out[d] = ab;
    wv_out[d] = s * wvr;
}

// ---------------- fold2: fold previous layer's BN into next W, b ----------------
__global__ void fold2_kernel(const float* __restrict__ W, const float* __restrict__ b,
                             const float* __restrict__ s_prev, const float* __restrict__ ab_prev,
                             float* __restrict__ Wp, float* __restrict__ bp) {
    int g = threadIdx.x; // 256 threads
    float bacc = b[g];
    for (int d = 0; d < HH; ++d) {
        float w = W[d * GG + g];
        bacc += ab_prev[d] * w;
        Wp[d * GG + g] = s_prev[d] * w;
    }
    bp[g] = bacc;
}

// ---------------- init per-call state ----------------
__global__ void init_kernel(float* st_h, float* st_c, float* st_acc, float* st_m, float* st_d) {
    int i = blockIdx.x * blockDim.x + threadIdx.x;
    int n = 3 * BB * HH;
    if (i < n) { st_h[i] = 0.f; st_c[i] = 0.f; st_acc[i] = 0.f; }
    if (i < 3 * BB) { st_m[i] = -3.0e38f; st_d[i] = 0.f; }
}

// ---------------- helpers ----------------
__device__ __forceinline__ f32x4 ld4(const float* p) { return *reinterpret_cast<const f32x4*>(p); }
__device__ __forceinline__ void st4(float* p, f32x4 v) { *reinterpret_cast<f32x4*>(p) = v; }
__device__ __forceinline__ int cvtpk(float a, float b) {
    int r; asm("v_cvt_pk_bf16_f32 %0, %1, %2" : "=v"(r) : "v"(a), "v"(b)); return r;
}
// split 8 fp32 (k-order) into hi/lo bf16x8 fragments (hi RNE; lo = residual)
__device__ __forceinline__ void mkfrag(f32x4 A, f32x4 B, bf16x8& hi, bf16x8& lo) {
    i32x4 H, L;
    H[0] = cvtpk(A[0], A[1]); H[1] = cvtpk(A[2], A[3]);
    H[2] = cvtpk(B[0], B[1]); H[3] = cvtpk(B[2], B[3]);
    L[0] = cvtpk(A[0] - __int_as_float(H[0] << 16), A[1] - __int_as_float(H[0] & 0xffff0000));
    L[1] = cvtpk(A[2] - __int_as_float(H[1] << 16), A[3] - __int_as_float(H[1] & 0xffff0000));
    L[2] = cvtpk(B[0] - __int_as_float(H[2] << 16), B[1] - __int_as_float(H[2] & 0xffff0000));
    L[3] = cvtpk(B[2] - __int_as_float(H[3] << 16), B[3] - __int_as_float(H[3] & 0xffff0000));
    hi = __builtin_bit_cast(bf16x8, H); lo = __builtin_bit_cast(bf16x8, L);
}
__device__ __forceinline__ float sigm(float x) { return __fdividef(1.f, 1.f + __expf(-x)); }
#define MFMA(a, b, c) c = __builtin_amdgcn_mfma_f32_16x16x32_bf16(a, b, c, 0, 0, 0)

// ---------------- prep: fp32 weight matrix -> hi/lo bf16 A-fragments, per-lane layout ----
// M: [K=32*KT][256]. Frag-pair f = (w*4+g)*KT + kt. Element (lane l, e):
//   src = M[32*kt + 8*(l>>4) + e][64*g + 16*w + (l&15)]
// out: hi frag at [(f*2+0)*512 + l*8 + e], lo at [(f*2+1)*512 + l*8 + e] (ushort bf16)
__global__ void prep_frags(const float* __restrict__ M, int KT, ushort_t* __restrict__ outF) {
    int idx = blockIdx.x * 256 + threadIdx.x;
    int tot = 16 * KT * 512;
    if (idx >= tot) return;
    int e = idx & 7, l = (idx >> 3) & 63, f = idx >> 9;
    int kt = f % KT, gw = f / KT;
    int g = gw & 3, w = gw >> 2;
    int r = l & 15, q = l >> 4;
    int k = 32 * kt + 8 * q + e;
    int col = 64 * g + 16 * w + r;
    float v = M[(size_t)k * GG + col];
    int hb = cvtpk(v, v) & 0xffff;
    float hf = __int_as_float(hb << 16);
    float lo = v - hf;
    int lb = cvtpk(lo, lo) & 0xffff;
    outF[(size_t)(f * 2 + 0) * 512 + l * 8 + e] = (ushort_t)hb;
    outF[(size_t)(f * 2 + 1) * 512 + l * 8 + e] = (ushort_t)lb;
}

// ---------------- MFMA recurrent kernel (pre-built fragments) ----------------
struct RecFArgs {
    const float* xin[3]; long sB[3]; long sT[3]; int K[3];
    const ushort_t* UF[3]; const ushort_t* WF[3]; const float* bias[3];
    float* Hout[3];              // nullptr -> skip
    float* st_h[3]; float* st_c[3]; float* st_acc[3];
    float* st_m[3]; float* st_d[3];
    const float* wv[3]; const float* abv[3]; const float* sbn[3];
    float* a_out[3];
    int last[3]; int first[3];
};

template<int KT>   // x K-tiles: 1 (K=32, layer1) or 2 (K=64)
__device__ __forceinline__ void rec_body(const RecFArgs& A, const int seg, const int b0,
                                         float (*hl)[MB][HPAD]) {
    const int tid = threadIdx.x;
    const int w = tid >> 6;
    const int l = tid & 63;
    const int r = l & 15;
    const int q = l >> 4;
    const int cw = w << 4;
    const int grow = b0 + r;

    // ---- fragment loads: one coalesced b128 per fragment ----
    const bf16x8* UF = reinterpret_cast<const bf16x8*>(A.UF[seg]);
    const bf16x8* WF = reinterpret_cast<const bf16x8*>(A.WF[seg]);
    bf16x8 UHf[4][2], ULf[4][2], WHf[4][KT], WLf[4][KT];
#pragma unroll
    for (int g = 0; g < 4; ++g) {
#pragma unroll
        for (int kt = 0; kt < 2; ++kt) {
            const int fU = (w * 4 + g) * 2 + kt;
            UHf[g][kt] = UF[(fU * 2 + 0) * 64 + l];
            ULf[g][kt] = UF[(fU * 2 + 1) * 64 + l];
        }
#pragma unroll
        for (int kt = 0; kt < KT; ++kt) {
            const int fW = (w * 4 + g) * KT + kt;
            WHf[g][kt] = WF[(fW * 2 + 0) * 64 + l];
            WLf[g][kt] = WF[(fW * 2 + 1) * 64 + l];
        }
    }
    f32x4 bias4[4];
#pragma unroll
    for (int g = 0; g < 4; ++g) bias4[g] = ld4(A.bias[seg] + 64 * g + cw + 4 * q);
    f32x4 wva = ld4(A.wv[seg] + 8 * q);
    f32x4 wvb = ld4(A.wv[seg] + 8 * q + 4);
    f32x4 wvc = ld4(A.wv[seg] + 32 + 8 * q);
    f32x4 wvd = ld4(A.wv[seg] + 32 + 8 * q + 4);

    f32x4 c4   = ld4(A.st_c[seg]   + (size_t)grow * HH + cw + 4 * q);
    f32x4 h4   = ld4(A.st_h[seg]   + (size_t)grow * HH + cw + 4 * q);
    f32x4 acc4 = ld4(A.st_acc[seg] + (size_t)grow * HH + cw + 4 * q);
    float m_b = A.st_m[seg][grow];
    float d_b = A.st_d[seg][grow];

    st4(&hl[0][r][cw + 4 * q], h4);

    const float* xbase = A.xin[seg] + (size_t)grow * A.sB[seg];
    const long sT = A.sT[seg];

    auto xload = [&](f32x4 (&X)[2 * KT], int t) {
        const float* xp = xbase + (size_t)t * sT + 8 * q;
        X[0] = ld4(xp); X[1] = ld4(xp + 4);
        if constexpr (KT == 2) { X[2] = ld4(xp + 32); X[3] = ld4(xp + 32 + 4); }
    };
    auto seed = [&](f32x4 (&C)[4], f32x4 (&X)[2 * KT]) {
        bf16x8 xh0, xl0, xh1, xl1;
        mkfrag(X[0], X[1], xh0, xl0);
        if constexpr (KT == 2) mkfrag(X[2], X[3], xh1, xl1);
#pragma unroll
        for (int g = 0; g < 4; ++g) {
            C[g] = bias4[g];
            MFMA(WHf[g][0], xh0, C[g]);
            MFMA(WHf[g][0], xl0, C[g]);
            MFMA(WLf[g][0], xh0, C[g]);
            if constexpr (KT == 2) {
                MFMA(WHf[g][1], xh1, C[g]);
                MFMA(WHf[g][1], xl1, C[g]);
                MFMA(WLf[g][1], xh1, C[g]);
            }
        }
    };
    auto attup = [&](f32x4 f0, f32x4 f1, f32x4 f2, f32x4 f3, f32x4 hp4) {
        float sc = 0.f;
#pragma unroll
        for (int i = 0; i < 4; ++i) {
            sc = fmaf(f0[i], wva[i], sc);
            sc = fmaf(f1[i], wvb[i], sc);
            sc = fmaf(f2[i], wvc[i], sc);
            sc = fmaf(f3[i], wvd[i], sc);
        }
        sc += __shfl_xor(sc, 16);
        sc += __shfl_xor(sc, 32);
        float mn = fmaxf(m_b, sc);
        float corr = __expf(m_b - mn);
        float p = __expf(sc - mn);
        d_b = d_b * corr + p;
        acc4 = acc4 * corr + p * hp4;
        m_b = mn;
    };

    // prologue: seed t=0; prefetch x1, x2
    f32x4 XA[2 * KT], XB[2 * KT];
    f32x4 Ca[4], Cb[4];
    xload(XA, 0);
    seed(Ca, XA);
    xload(XA, 1);
    xload(XB, 2);
    __syncthreads();

    const bool first = A.first[seg] != 0;
    float* Hob = A.Hout[seg];

    auto STEP = [&](int t, f32x4 (&Cc)[4], f32x4 (&Cn)[4], f32x4 (&X)[2 * KT]) {
        const int pr = t & 1;
        f32x4 f0 = ld4(&hl[pr][r][8 * q]);
        f32x4 f1 = ld4(&hl[pr][r][8 * q + 4]);
        f32x4 f2 = ld4(&hl[pr][r][32 + 8 * q]);
        f32x4 f3 = ld4(&hl[pr][r][32 + 8 * q + 4]);
        f32x4 hp4 = ld4(&hl[pr][r][cw + 4 * q]);
        bf16x8 bh0, bl0, bh1, bl1;
        mkfrag(f0, f1, bh0, bl0);
        mkfrag(f2, f3, bh1, bl1);
        // U-MFMAs (dependent chain per gate-group; 4 groups interleave)
#pragma unroll
        for (int g = 0; g < 4; ++g) {
            MFMA(UHf[g][0], bh0, Cc[g]);
            MFMA(UHf[g][0], bl0, Cc[g]);
            MFMA(ULf[g][0], bh0, Cc[g]);
            MFMA(UHf[g][1], bh1, Cc[g]);
            MFMA(UHf[g][1], bl1, Cc[g]);
            MFMA(ULf[g][1], bh1, Cc[g]);
        }
        // independent work under the MFMA shadow:
        seed(Cn, X);                              // z_x(t+1)
        if (!(first && t == 0)) attup(f0, f1, f2, f3, hp4);
        { int tn = t + 3 < TC ? t + 3 : TC - 1; xload(X, tn); }
        // activation (first read of Cc stalls here)
#pragma unroll
        for (int i = 0; i < 4; ++i) {
            float zi = sigm(Cc[0][i]);
            float zf = sigm(Cc[1][i]);
            float zg = fmaxf(Cc[2][i], 0.f);
            float zo = sigm(Cc[3][i]);
            c4[i] = fmaf(zf, c4[i], zi * zg);
            h4[i] = zo * fmaxf(c4[i], 0.f);
        }
        st4(&hl[pr ^ 1][r][cw + 4 * q], h4);
        if (Hob) st4(Hob + (size_t)grow * (TC * HH) + (size_t)t * HH + cw + 4 * q, h4);
        __syncthreads();
    };

#pragma unroll 1
    for (int it = 0; it < TC / 2; ++it) {
        STEP(2 * it,     Ca, Cb, XA);
        STEP(2 * it + 1, Cb, Ca, XB);
    }

    // epilogue: last chunk scores h_{TC-1} (sits in hl[0], TC even) and emits output
    if (A.last[seg]) {
        f32x4 f0 = ld4(&hl[0][r][8 * q]);
        f32x4 f1 = ld4(&hl[0][r][8 * q + 4]);
        f32x4 f2 = ld4(&hl[0][r][32 + 8 * q]);
        f32x4 f3 = ld4(&hl[0][r][32 + 8 * q + 4]);
        attup(f0, f1, f2, f3, h4);
        f32x4 sb = ld4(A.sbn[seg] + cw + 4 * q);
        f32x4 ab = ld4(A.abv[seg] + cw + 4 * q);
        f32x4 res;
#pragma unroll
        for (int i = 0; i < 4; ++i)
            res[i] = sb[i] * __fdividef(acc4[i], d_b) + ab[i];
        st4(A.a_out[seg] + (size_t)grow * HH + cw + 4 * q, res);
    }
    st4(A.st_c[seg]   + (size_t)grow * HH + cw + 4 * q, c4);
    st4(A.st_h[seg]   + (size_t)grow * HH + cw + 4 * q, h4);
    st4(A.st_acc[seg] + (size_t)grow * HH + cw + 4 * q, acc4);
    if (w == 0 && q == 0) { A.st_m[seg][grow] = m_b; A.st_d[seg][grow] = d_b; }
}

__global__ __launch_bounds__(256, 1) void rec_mfma(RecFArgs A) {
    __shared__ float hl[2][MB][HPAD];   // 8.7 KB
    const int seg = blockIdx.x >> 6;             // NBLK = 64
    const int b0 = (blockIdx.x & (NBLK - 1)) << 4;
    if (A.K[seg] == 32) rec_body<1>(A, seg, b0, hl);
    else                rec_body<2>(A, seg, b0, hl);
}

// ---------------- final: out[b] = db + sum_{l,j} a[l][b][j]*dw[l*64+j] ----------------
__global__ void final_kernel(const float* __restrict__ a, const float* __restrict__ dw,
                             const float* __restrict__ db, float* __restrict__ out) {
    int b = blockIdx.x * blockDim.x + threadIdx.x;
    if (b >= BB) return;
    float acc = db[0];
    for (int l = 0; l < 3; ++l)
        for (int j = 0; j < HH; ++j)
            acc += a[(l * BB + b) * HH + j] * dw[l * HH + j];
    out[b] = acc;
}

extern "C" void kernel_launch(void* const* d_in, const int* in_sizes, int n_in,
                              void* d_out, int out_size, void* d_ws, size_t ws_size,
                              hipStream_t stream) {
    (void)in_sizes; (void)n_in; (void)out_size; (void)ws_size;
    const float* x = (const float*)d_in[0];
    const float* w[3]    = {(const float*)d_in[1],  (const float*)d_in[10], (const float*)d_in[19]};
    const float* uu[3]   = {(const float*)d_in[2],  (const float*)d_in[11], (const float*)d_in[20]};
    const float* bi[3]   = {(const float*)d_in[3],  (const float*)d_in[12], (const float*)d_in[21]};
    const float* gam[3]  = {(const float*)d_in[4],  (const float*)d_in[13], (const float*)d_in[22]};
    const float* bet[3]  = {(const float*)d_in[5],  (const float*)d_in[14], (const float*)d_in[23]};
    const float* mea[3]  = {(const float*)d_in[6],  (const float*)d_in[15], (const float*)d_in[24]};
    const float* var[3]  = {(const float*)d_in[7],  (const float*)d_in[16], (const float*)d_in[25]};
    const float* atw[3]  = {(const float*)d_in[8],  (const float*)d_in[17], (const float*)d_in[26]};
    const float* atv[3]  = {(const float*)d_in[9],  (const float*)d_in[18], (const float*)d_in[27]};
    const float* dw = (const float*)d_in[28];
    const float* db = (const float*)d_in[29];

    float* ws = (float*)d_ws;
    size_t off = 0;
    float* Hb[2][2];
    for (int l = 0; l < 2; ++l)
        for (int p = 0; p < 2; ++p) { Hb[l][p] = ws + off; off += (size_t)BB * TC * HH; }
    float* st_h  = ws + off; off += 3 * BB * HH;
    float* st_c  = ws + off; off += 3 * BB * HH;
    float* st_ac = ws + off; off += 3 * BB * HH;
    float* st_m  = ws + off; off += 3 * BB;
    float* st_d  = ws + off; off += 3 * BB;
    float* s_ws  = ws + off; off += 3 * HH;
    float* ab_ws = ws + off; off += 3 * HH;
    float* wv_ws = ws + off; off += 3 * HH;
    float* W2p   = ws + off; off += HH * GG;
    float* W3p   = ws + off; off += HH * GG;
    float* b2p   = ws + off; off += GG;
    float* b3p   = ws + off; off += GG;
    float* a_ws  = ws + off; off += 3 * BB * HH;
    ushort_t* UFb[3]; ushort_t* WFb[3];
    for (int l = 0; l < 3; ++l) { UFb[l] = (ushort_t*)(ws + off); off += 16384; }  // 64KB each
    for (int l = 0; l < 3; ++l) { WFb[l] = (ushort_t*)(ws + off); off += 16384; }

    for (int l = 0; l < 3; ++l)
        fold1_kernel<<<1, 64, 0, stream>>>(gam[l], bet[l], mea[l], var[l], atw[l], atv[l],
                                           s_ws + l * HH, ab_ws + l * HH, wv_ws + l * HH);
    fold2_kernel<<<1, 256, 0, stream>>>(w[1], bi[1], s_ws + 0 * HH, ab_ws + 0 * HH, W2p, b2p);
    fold2_kernel<<<1, 256, 0, stream>>>(w[2], bi[2], s_ws + 1 * HH, ab_ws + 1 * HH, W3p, b3p);
    init_kernel<<<(3 * BB * HH + 255) / 256, 256, 0, stream>>>(st_h, st_c, st_ac, st_m, st_d);

    // pre-build bf16 hi/lo weight fragments
    for (int l = 0; l < 3; ++l)
        prep_frags<<<64, 256, 0, stream>>>(uu[l], 2, UFb[l]);
    prep_frags<<<32, 256, 0, stream>>>(w[0], 1, WFb[0]);
    prep_frags<<<64, 256, 0, stream>>>(W2p, 2, WFb[1]);
    prep_frags<<<64, 256, 0, stream>>>(W3p, 2, WFb[2]);

    const float* bl[3] = {bi[0], b2p, b3p};

    // software pipeline: at step s, layer l processes chunk s-l
    for (int s = 0; s <= NCHUNK - 1 + 2; ++s) {
        RecFArgs ra;
        int nseg = 0;
        for (int l = 0; l < 3; ++l) {
            int cpos = s - l;
            if (cpos < 0 || cpos >= NCHUNK) continue;
            if (l == 0) {
                ra.xin[nseg] = x + (size_t)cpos * TC * FF;
                ra.sB[nseg] = (long)TT * FF;
                ra.sT[nseg] = FF;
                ra.K[nseg] = 32;
            } else {
                ra.xin[nseg] = Hb[l - 1][(s & 1) ^ 1];   // written by layer l-1 at step s-1
                ra.sB[nseg] = (long)TC * HH;
                ra.sT[nseg] = HH;
                ra.K[nseg] = 64;
            }
            ra.UF[nseg] = UFb[l]; ra.WF[nseg] = WFb[l]; ra.bias[nseg] = bl[l];
            ra.Hout[nseg] = (l < 2) ? Hb[l][s & 1] : (float*)0;
            ra.st_h[nseg] = st_h + l * BB * HH;
            ra.st_c[nseg] = st_c + l * BB * HH;
            ra.st_acc[nseg] = st_ac + l * BB * HH;
            ra.st_m[nseg] = st_m + l * BB;
            ra.st_d[nseg] = st_d + l * BB;
            ra.wv[nseg]  = wv_ws + l * HH;
            ra.abv[nseg] = ab_ws + l * HH;
            ra.sbn[nseg] = s_ws + l * HH;
            ra.a_out[nseg] = a_ws + l * BB * HH;
            ra.last[nseg]  = (cpos == NCHUNK - 1) ? 1 : 0;
            ra.first[nseg] = (cpos == 0) ? 1 : 0;
            ++nseg;
        }
        if (!nseg) continue;
        rec_mfma<<<nseg * NBLK, 256, 0, stream>>>(ra);
    }
    final_kernel<<<(BB + 255) / 256, 256, 0, stream>>>(a_ws, dw, db, (float*)d_out);
}

// Round 10
// 788.969 us; speedup vs baseline: 1.3625x; 1.0142x over previous
//
#include <hip/hip_runtime.h>
#include <math.h>

#define BB 1024
#define TT 512
#define FF 32
#define HH 64
#define GG 256   // 4H
#define TC 64
#define NCHUNK (TT/TC)   // 8
#define MB 16            // batch rows per block
#define NBLK (BB/MB)     // 64
#define HPAD 68          // h_lds row stride
#define EPSBN 1e-3f

typedef __attribute__((ext_vector_type(8))) short bf16x8;
typedef __attribute__((ext_vector_type(4))) float f32x4;
typedef __attribute__((ext_vector_type(4))) int   i32x4;
typedef unsigned short ushort_t;

// ---------------- fold1: per-layer BN vectors + attention vector ----------------
__global__ void fold1_kernel(const float* __restrict__ gamma, const float* __restrict__ beta,
                             const float* __restrict__ mean, const float* __restrict__ var,
                             const float* __restrict__ attw, const float* __restrict__ attv,
                             float* __restrict__ s_out, float* __restrict__ ab_out,
                             float* __restrict__ wv_out) {
    int d = threadIdx.x; // 64 threads
    float s = gamma[d] * rsqrtf(var[d] + EPSBN);
    float ab = beta[d] - mean[d] * s;
    float wvr = 0.f;
    for (int e = 0; e < HH; ++e) wvr += attw[d * HH + e] * attv[e];
    s_out[d] = s;
    ab_out[d] = ab;
    wv_out[d] = s * wvr;
}

// ---------------- fold2: fold previous layer's BN into next W, b ----------------
__global__ void fold2_kernel(const float* __restrict__ W, const float* __restrict__ b,
                             const float* __restrict__ s_prev, const float* __restrict__ ab_prev,
                             float* __restrict__ Wp, float* __restrict__ bp) {
    int g = threadIdx.x; // 256 threads
    float bacc = b[g];
    for (int d = 0; d < HH; ++d) {
        float w = W[d * GG + g];
        bacc += ab_prev[d] * w;
        Wp[d * GG + g] = s_prev[d] * w;
    }
    bp[g] = bacc;
}

// ---------------- init per-call state ----------------
__global__ void init_kernel(float* st_h, float* st_c, float* st_acc, float* st_m, float* st_d) {
    int i = blockIdx.x * blockDim.x + threadIdx.x;
    int n = 3 * BB * HH;
    if (i < n) { st_h[i] = 0.f; st_c[i] = 0.f; st_acc[i] = 0.f; }
    if (i < 3 * BB) { st_m[i] = -3.0e38f; st_d[i] = 0.f; }
}

// ---------------- helpers ----------------
__device__ __forceinline__ f32x4 ld4(const float* p) { return *reinterpret_cast<const f32x4*>(p); }
__device__ __forceinline__ void st4(float* p, f32x4 v) { *reinterpret_cast<f32x4*>(p) = v; }
__device__ __forceinline__ int cvtpk(float a, float b) {
    int r; asm("v_cvt_pk_bf16_f32 %0, %1, %2" : "=v"(r) : "v"(a), "v"(b)); return r;
}
// split 8 fp32 (k-order) into hi/lo bf16x8 fragments (hi RNE; lo = residual)
__device__ __forceinline__ void mkfrag(f32x4 A, f32x4 B, bf16x8& hi, bf16x8& lo) {
    i32x4 H, L;
    H[0] = cvtpk(A[0], A[1]); H[1] = cvtpk(A[2], A[3]);
    H[2] = cvtpk(B[0], B[1]); H[3] = cvtpk(B[2], B[3]);
    L[0] = cvtpk(A[0] - __int_as_float(H[0] << 16), A[1] - __int_as_float(H[0] & 0xffff0000));
    L[1] = cvtpk(A[2] - __int_as_float(H[1] << 16), A[3] - __int_as_float(H[1] & 0xffff0000));
    L[2] = cvtpk(B[0] - __int_as_float(H[2] << 16), B[1] - __int_as_float(H[2] & 0xffff0000));
    L[3] = cvtpk(B[2] - __int_as_float(H[3] << 16), B[3] - __int_as_float(H[3] & 0xffff0000));
    hi = __builtin_bit_cast(bf16x8, H); lo = __builtin_bit_cast(bf16x8, L);
}
__device__ __forceinline__ float sigm(float x) { return __fdividef(1.f, 1.f + __expf(-x)); }
#define MFMA(a, b, c) c = __builtin_amdgcn_mfma_f32_16x16x32_bf16(a, b, c, 0, 0, 0)
#define PIN(x) asm volatile("" : "+v"(x))

// ---------------- prep: fp32 weight matrix -> hi/lo bf16 A-fragments, per-lane layout ----
__global__ void prep_frags(const float* __restrict__ M, int KT, ushort_t* __restrict__ outF) {
    int idx = blockIdx.x * 256 + threadIdx.x;
    int tot = 16 * KT * 512;
    if (idx >= tot) return;
    int e = idx & 7, l = (idx >> 3) & 63, f = idx >> 9;
    int kt = f % KT, gw = f / KT;
    int g = gw & 3, w = gw >> 2;
    int r = l & 15, q = l >> 4;
    int k = 32 * kt + 8 * q + e;
    int col = 64 * g + 16 * w + r;
    float v = M[(size_t)k * GG + col];
    int hb = cvtpk(v, v) & 0xffff;
    float hf = __int_as_float(hb << 16);
    float lo = v - hf;
    int lb = cvtpk(lo, lo) & 0xffff;
    outF[(size_t)(f * 2 + 0) * 512 + l * 8 + e] = (ushort_t)hb;
    outF[(size_t)(f * 2 + 1) * 512 + l * 8 + e] = (ushort_t)lb;
}

// ---------------- MFMA recurrent kernel: flattened, named+pinned fragments ----------------
struct RecFArgs {
    const float* xin[3]; long sB[3]; long sT[3]; int K[3];
    const ushort_t* UF[3]; const ushort_t* WF[3]; const float* bias[3];
    float* Hout[3];              // nullptr -> skip
    float* st_h[3]; float* st_c[3]; float* st_acc[3];
    float* st_m[3]; float* st_d[3];
    const float* wv[3]; const float* abv[3]; const float* sbn[3];
    float* a_out[3];
    int last[3]; int first[3];
};

template<int KT>   // x K-tiles: 1 (K=32, layer1) or 2 (K=64)
__device__ __forceinline__ void rec_body(const RecFArgs& A, const int seg, const int b0,
                                         float (*hl)[MB][HPAD]) {
    const int tid = threadIdx.x;
    const int w = tid >> 6;
    const int l = tid & 63;
    const int r = l & 15;
    const int q = l >> 4;
    const int cw = w << 4;
    const int grow = b0 + r;

    const bf16x8* UF = reinterpret_cast<const bf16x8*>(A.UF[seg]);
    const bf16x8* WF = reinterpret_cast<const bf16x8*>(A.WF[seg]);
#define LDU(g,kt,hl_) UF[(((((w<<2)+(g))*2+(kt))*2)+(hl_))*64 + l]
#define LDW(g,kt,hl_) WF[(((((w<<2)+(g))*KT+(kt))*2)+(hl_))*64 + l]
    bf16x8 uh00=LDU(0,0,0), uh01=LDU(0,1,0), uh10=LDU(1,0,0), uh11=LDU(1,1,0),
           uh20=LDU(2,0,0), uh21=LDU(2,1,0), uh30=LDU(3,0,0), uh31=LDU(3,1,0);
    bf16x8 ul00=LDU(0,0,1), ul01=LDU(0,1,1), ul10=LDU(1,0,1), ul11=LDU(1,1,1),
           ul20=LDU(2,0,1), ul21=LDU(2,1,1), ul30=LDU(3,0,1), ul31=LDU(3,1,1);
    bf16x8 wh00=LDW(0,0,0), wh10=LDW(1,0,0), wh20=LDW(2,0,0), wh30=LDW(3,0,0);
    bf16x8 wl00=LDW(0,0,1), wl10=LDW(1,0,1), wl20=LDW(2,0,1), wl30=LDW(3,0,1);
    bf16x8 wh01{}, wh11{}, wh21{}, wh31{}, wl01{}, wl11{}, wl21{}, wl31{};
    if constexpr (KT == 2) {
        wh01=LDW(0,1,0); wh11=LDW(1,1,0); wh21=LDW(2,1,0); wh31=LDW(3,1,0);
        wl01=LDW(0,1,1); wl11=LDW(1,1,1); wl21=LDW(2,1,1); wl31=LDW(3,1,1);
    }
    PIN(uh00);PIN(uh01);PIN(uh10);PIN(uh11);PIN(uh20);PIN(uh21);PIN(uh30);PIN(uh31);
    PIN(ul00);PIN(ul01);PIN(ul10);PIN(ul11);PIN(ul20);PIN(ul21);PIN(ul30);PIN(ul31);
    PIN(wh00);PIN(wh10);PIN(wh20);PIN(wh30);
    PIN(wl00);PIN(wl10);PIN(wl20);PIN(wl30);
    if constexpr (KT == 2) {
        PIN(wh01);PIN(wh11);PIN(wh21);PIN(wh31);
        PIN(wl01);PIN(wl11);PIN(wl21);PIN(wl31);
    }

    f32x4 bias40 = ld4(A.bias[seg] +   0 + cw + 4 * q);
    f32x4 bias41 = ld4(A.bias[seg] +  64 + cw + 4 * q);
    f32x4 bias42 = ld4(A.bias[seg] + 128 + cw + 4 * q);
    f32x4 bias43 = ld4(A.bias[seg] + 192 + cw + 4 * q);
    f32x4 wva = ld4(A.wv[seg] + 8 * q);
    f32x4 wvb = ld4(A.wv[seg] + 8 * q + 4);
    f32x4 wvc = ld4(A.wv[seg] + 32 + 8 * q);
    f32x4 wvd = ld4(A.wv[seg] + 32 + 8 * q + 4);

    f32x4 c4   = ld4(A.st_c[seg]   + (size_t)grow * HH + cw + 4 * q);
    f32x4 h4   = ld4(A.st_h[seg]   + (size_t)grow * HH + cw + 4 * q);
    f32x4 acc4 = ld4(A.st_acc[seg] + (size_t)grow * HH + cw + 4 * q);
    float m_b = A.st_m[seg][grow];
    float d_b = A.st_d[seg][grow];

    st4(&hl[0][r][cw + 4 * q], h4);

    const float* xbase = A.xin[seg] + (size_t)grow * A.sB[seg];
    const long sT = A.sT[seg];

    // prologue: x for t=0
    f32x4 x0, x1, x2{}, x3{};
    {
        const float* xp = xbase + 8 * q;
        x0 = ld4(xp); x1 = ld4(xp + 4);
        if constexpr (KT == 2) { x2 = ld4(xp + 32); x3 = ld4(xp + 36); }
    }
    __syncthreads();

    const bool first = A.first[seg] != 0;
    float* Hob = A.Hout[seg];

#pragma unroll 2
    for (int t = 0; t < TC; ++t) {
        const int pr = t & 1;
        // prefetch next x (clamped)
        const int tn = (t + 1 < TC) ? t + 1 : TC - 1;
        const float* xp = xbase + (size_t)tn * sT + 8 * q;
        f32x4 n0 = ld4(xp), n1 = ld4(xp + 4), n2{}, n3{};
        if constexpr (KT == 2) { n2 = ld4(xp + 32); n3 = ld4(xp + 36); }

        // LDS reads: full h row (for frag + attention) and own slice
        f32x4 f0 = ld4(&hl[pr][r][8 * q]);
        f32x4 f1 = ld4(&hl[pr][r][8 * q + 4]);
        f32x4 f2 = ld4(&hl[pr][r][32 + 8 * q]);
        f32x4 f3 = ld4(&hl[pr][r][32 + 8 * q + 4]);
        f32x4 hp4 = ld4(&hl[pr][r][cw + 4 * q]);

        bf16x8 bh0, bl0, bh1, bl1, xh0, xl0, xh1, xl1;
        mkfrag(f0, f1, bh0, bl0);
        mkfrag(f2, f3, bh1, bl1);
        mkfrag(x0, x1, xh0, xl0);
        if constexpr (KT == 2) mkfrag(x2, x3, xh1, xl1);

        // gate 0 (same accumulation order as r9: W kt0, W kt1, U kt0, U kt1)
        f32x4 C0 = bias40;
        MFMA(wh00, xh0, C0); MFMA(wh00, xl0, C0); MFMA(wl00, xh0, C0);
        if constexpr (KT == 2) { MFMA(wh01, xh1, C0); MFMA(wh01, xl1, C0); MFMA(wl01, xh1, C0); }
        MFMA(uh00, bh0, C0); MFMA(uh00, bl0, C0); MFMA(ul00, bh0, C0);
        MFMA(uh01, bh1, C0); MFMA(uh01, bl1, C0); MFMA(ul01, bh1, C0);
        // gate 1
        f32x4 C1 = bias41;
        MFMA(wh10, xh0, C1); MFMA(wh10, xl0, C1); MFMA(wl10, xh0, C1);
        if constexpr (KT == 2) { MFMA(wh11, xh1, C1); MFMA(wh11, xl1, C1); MFMA(wl11, xh1, C1); }
        MFMA(uh10, bh0, C1); MFMA(uh10, bl0, C1); MFMA(ul10, bh0, C1);
        MFMA(uh11, bh1, C1); MFMA(uh11, bl1, C1); MFMA(ul11, bh1, C1);
        // gate 2
        f32x4 C2 = bias42;
        MFMA(wh20, xh0, C2); MFMA(wh20, xl0, C2); MFMA(wl20, xh0, C2);
        if constexpr (KT == 2) { MFMA(wh21, xh1, C2); MFMA(wh21, xl1, C2); MFMA(wl21, xh1, C2); }
        MFMA(uh20, bh0, C2); MFMA(uh20, bl0, C2); MFMA(ul20, bh0, C2);
        MFMA(uh21, bh1, C2); MFMA(uh21, bl1, C2); MFMA(ul21, bh1, C2);
        // gate 3
        f32x4 C3 = bias43;
        MFMA(wh30, xh0, C3); MFMA(wh30, xl0, C3); MFMA(wl30, xh0, C3);
        if constexpr (KT == 2) { MFMA(wh31, xh1, C3); MFMA(wh31, xl1, C3); MFMA(wl31, xh1, C3); }
        MFMA(uh30, bh0, C3); MFMA(uh30, bl0, C3); MFMA(ul30, bh0, C3);
        MFMA(uh31, bh1, C3); MFMA(uh31, bl1, C3); MFMA(ul31, bh1, C3);

        // online-softmax attention on h_{t-1} (independent of MFMA results)
        if (!(first && t == 0)) {
            float sc = 0.f;
#pragma unroll
            for (int i = 0; i < 4; ++i) {
                sc = fmaf(f0[i], wva[i], sc);
                sc = fmaf(f1[i], wvb[i], sc);
                sc = fmaf(f2[i], wvc[i], sc);
                sc = fmaf(f3[i], wvd[i], sc);
            }
            sc += __shfl_xor(sc, 16);
            sc += __shfl_xor(sc, 32);
            float mn = fmaxf(m_b, sc);
            float corr = __expf(m_b - mn);
            float p = __expf(sc - mn);
            d_b = d_b * corr + p;
            acc4 = acc4 * corr + p * hp4;
            m_b = mn;
        }

        // activation + state update
#pragma unroll
        for (int i = 0; i < 4; ++i) {
            float zi = sigm(C0[i]);
            float zf = sigm(C1[i]);
            float zg = fmaxf(C2[i], 0.f);
            float zo = sigm(C3[i]);
            c4[i] = fmaf(zf, c4[i], zi * zg);
            h4[i] = zo * fmaxf(c4[i], 0.f);
        }
        st4(&hl[pr ^ 1][r][cw + 4 * q], h4);
        if (Hob) st4(Hob + (size_t)grow * (TC * HH) + (size_t)t * HH + cw + 4 * q, h4);

        x0 = n0; x1 = n1;
        if constexpr (KT == 2) { x2 = n2; x3 = n3; }
        __syncthreads();
    }

    // epilogue: last chunk scores h_{TC-1} (in hl[0], TC even) and emits output
    if (A.last[seg]) {
        f32x4 f0 = ld4(&hl[0][r][8 * q]);
        f32x4 f1 = ld4(&hl[0][r][8 * q + 4]);
        f32x4 f2 = ld4(&hl[0][r][32 + 8 * q]);
        f32x4 f3 = ld4(&hl[0][r][32 + 8 * q + 4]);
        float sc = 0.f;
#pragma unroll
        for (int i = 0; i < 4; ++i) {
            sc = fmaf(f0[i], wva[i], sc);
            sc = fmaf(f1[i], wvb[i], sc);
            sc = fmaf(f2[i], wvc[i], sc);
            sc = fmaf(f3[i], wvd[i], sc);
        }
        sc += __shfl_xor(sc, 16);
        sc += __shfl_xor(sc, 32);
        float mn = fmaxf(m_b, sc);
        float corr = __expf(m_b - mn);
        float p = __expf(sc - mn);
        d_b = d_b * corr + p;
        acc4 = acc4 * corr + p * h4;
        m_b = mn;
        f32x4 sb = ld4(A.sbn[seg] + cw + 4 * q);
        f32x4 ab = ld4(A.abv[seg] + cw + 4 * q);
        f32x4 res;
#pragma unroll
        for (int i = 0; i < 4; ++i)
            res[i] = sb[i] * __fdividef(acc4[i], d_b) + ab[i];
        st4(A.a_out[seg] + (size_t)grow * HH + cw + 4 * q, res);
    }
    st4(A.st_c[seg]   + (size_t)grow * HH + cw + 4 * q, c4);
    st4(A.st_h[seg]   + (size_t)grow * HH + cw + 4 * q, h4);
    st4(A.st_acc[seg] + (size_t)grow * HH + cw + 4 * q, acc4);
    if (w == 0 && q == 0) { A.st_m[seg][grow] = m_b; A.st_d[seg][grow] = d_b; }
#undef LDU
#undef LDW
}

__global__ __launch_bounds__(256, 1) void rec_mfma(RecFArgs A) {
    __shared__ float hl[2][MB][HPAD];   // 8.7 KB
    const int seg = blockIdx.x >> 6;             // NBLK = 64
    const int b0 = (blockIdx.x & (NBLK - 1)) << 4;
    if (A.K[seg] == 32) rec_body<1>(A, seg, b0, hl);
    else                rec_body<2>(A, seg, b0, hl);
}

// ---------------- final: out[b] = db + sum_{l,j} a[l][b][j]*dw[l*64+j] ----------------
__global__ void final_kernel(const float* __restrict__ a, const float* __restrict__ dw,
                             const float* __restrict__ db, float* __restrict__ out) {
    int b = blockIdx.x * blockDim.x + threadIdx.x;
    if (b >= BB) return;
    float acc = db[0];
    for (int l = 0; l < 3; ++l)
        for (int j = 0; j < HH; ++j)
            acc += a[(l * BB + b) * HH + j] * dw[l * HH + j];
    out[b] = acc;
}

extern "C" void kernel_launch(void* const* d_in, const int* in_sizes, int n_in,
                              void* d_out, int out_size, void* d_ws, size_t ws_size,
                              hipStream_t stream) {
    (void)in_sizes; (void)n_in; (void)out_size; (void)ws_size;
    const float* x = (const float*)d_in[0];
    const float* w[3]    = {(const float*)d_in[1],  (const float*)d_in[10], (const float*)d_in[19]};
    const float* uu[3]   = {(const float*)d_in[2],  (const float*)d_in[11], (const float*)d_in[20]};
    const float* bi[3]   = {(const float*)d_in[3],  (const float*)d_in[12], (const float*)d_in[21]};
    const float* gam[3]  = {(const float*)d_in[4],  (const float*)d_in[13], (const float*)d_in[22]};
    const float* bet[3]  = {(const float*)d_in[5],  (const float*)d_in[14], (const float*)d_in[23]};
    const float* mea[3]  = {(const float*)d_in[6],  (const float*)d_in[15], (const float*)d_in[24]};
    const float* var[3]  = {(const float*)d_in[7],  (const float*)d_in[16], (const float*)d_in[25]};
    const float* atw[3]  = {(const float*)d_in[8],  (const float*)d_in[17], (const float*)d_in[26]};
    const float* atv[3]  = {(const float*)d_in[9],  (const float*)d_in[18], (const float*)d_in[27]};
    const float* dw = (const float*)d_in[28];
    const float* db = (const float*)d_in[29];

    float* ws = (float*)d_ws;
    size_t off = 0;
    float* Hb[2][2];
    for (int l = 0; l < 2; ++l)
        for (int p = 0; p < 2; ++p) { Hb[l][p] = ws + off; off += (size_t)BB * TC * HH; }
    float* st_h  = ws + off; off += 3 * BB * HH;
    float* st_c  = ws + off; off += 3 * BB * HH;
    float* st_ac = ws + off; off += 3 * BB * HH;
    float* st_m  = ws + off; off += 3 * BB;
    float* st_d  = ws + off; off += 3 * BB;
    float* s_ws  = ws + off; off += 3 * HH;
    float* ab_ws = ws + off; off += 3 * HH;
    float* wv_ws = ws + off; off += 3 * HH;
    float* W2p   = ws + off; off += HH * GG;
    float* W3p   = ws + off; off += HH * GG;
    float* b2p   = ws + off; off += GG;
    float* b3p   = ws + off; off += GG;
    float* a_ws  = ws + off; off += 3 * BB * HH;
    ushort_t* UFb[3]; ushort_t* WFb[3];
    for (int l = 0; l < 3; ++l) { UFb[l] = (ushort_t*)(ws + off); off += 16384; }  // 64KB each
    for (int l = 0; l < 3; ++l) { WFb[l] = (ushort_t*)(ws + off); off += 16384; }

    for (int l = 0; l < 3; ++l)
        fold1_kernel<<<1, 64, 0, stream>>>(gam[l], bet[l], mea[l], var[l], atw[l], atv[l],
                                           s_ws + l * HH, ab_ws + l * HH, wv_ws + l * HH);
    fold2_kernel<<<1, 256, 0, stream>>>(w[1], bi[1], s_ws + 0 * HH, ab_ws + 0 * HH, W2p, b2p);
    fold2_kernel<<<1, 256, 0, stream>>>(w[2], bi[2], s_ws + 1 * HH, ab_ws + 1 * HH, W3p, b3p);
    init_kernel<<<(3 * BB * HH + 255) / 256, 256, 0, stream>>>(st_h, st_c, st_ac, st_m, st_d);

    // pre-build bf16 hi/lo weight fragments
    for (int l = 0; l < 3; ++l)
        prep_frags<<<64, 256, 0, stream>>>(uu[l], 2, UFb[l]);
    prep_frags<<<32, 256, 0, stream>>>(w[0], 1, WFb[0]);
    prep_frags<<<64, 256, 0, stream>>>(W2p, 2, WFb[1]);
    prep_frags<<<64, 256, 0, stream>>>(W3p, 2, WFb[2]);

    const float* bl[3] = {bi[0], b2p, b3p};

    // software pipeline: at step s, layer l processes chunk s-l
    for (int s = 0; s <= NCHUNK - 1 + 2; ++s) {
        RecFArgs ra;
        int nseg = 0;
        for (int l = 0; l < 3; ++l) {
            int cpos = s - l;
            if (cpos < 0 || cpos >= NCHUNK) continue;
            if (l == 0) {
                ra.xin[nseg] = x + (size_t)cpos * TC * FF;
                ra.sB[nseg] = (long)TT * FF;
                ra.sT[nseg] = FF;
                ra.K[nseg] = 32;
            } else {
                ra.xin[nseg] = Hb[l - 1][(s & 1) ^ 1];   // written by layer l-1 at step s-1
                ra.sB[nseg] = (long)TC * HH;
                ra.sT[nseg] = HH;
                ra.K[nseg] = 64;
            }
            ra.UF[nseg] = UFb[l]; ra.WF[nseg] = WFb[l]; ra.bias[nseg] = bl[l];
            ra.Hout[nseg] = (l < 2) ? Hb[l][s & 1] : (float*)0;
            ra.st_h[nseg] = st_h + l * BB * HH;
            ra.st_c[nseg] = st_c + l * BB * HH;
            ra.st_acc[nseg] = st_ac + l * BB * HH;
            ra.st_m[nseg] = st_m + l * BB;
            ra.st_d[nseg] = st_d + l * BB;
            ra.wv[nseg]  = wv_ws + l * HH;
            ra.abv[nseg] = ab_ws + l * HH;
            ra.sbn[nseg] = s_ws + l * HH;
            ra.a_out[nseg] = a_ws + l * BB * HH;
            ra.last[nseg]  = (cpos == NCHUNK - 1) ? 1 : 0;
            ra.first[nseg] = (cpos == 0) ? 1 : 0;
            ++nseg;
        }
        if (!nseg) continue;
        rec_mfma<<<nseg * NBLK, 256, 0, stream>>>(ra);
    }
    final_kernel<<<(BB + 255) / 256, 256, 0, stream>>>(a_ws, dw, db, (float*)d_out);
}